// Round 1
// 226.571 us; speedup vs baseline: 1.0111x; 1.0111x over previous
//
#include <hip/hip_runtime.h>

// FWHT over last dim 4096 of fp32 tensor, rows = total/4096.
// Radix-16^3 decomposition: one 256-thread block (4 waves) per row, each
// thread holds 16 floats. Three 4-bit register FWHT phases (bits 0-3, 4-7,
// 8-11) with two LDS transposes in between. Stage order is ascending bit
// order with identical butterfly pairings/operand roles as the reference,
// so results are bit-identical to the float32 reference (absmax = 0).
//
// Rationale vs previous 64-lane/row version (81 us/dispatch, Occ 16%,
// VALUBusy 11%, HBM 31%): that kernel was latency-bound — 1 wave/block with
// 17.4 KB LDS capped residency at ~9 waves/CU. This shape keeps LDS at
// 17.4 KB but packs 4 waves/block at ~40 VGPR, so occupancy is capped by
// the 2048-thread/CU limit: 8 blocks x 4 waves = 32 waves/CU (100%).
//
// LDS layouts (pitch-17, all accesses <=2-way bank aliasing = free):
//   T1: element n at buf[17*(n>>4) + (n&15)]
//       write: thread t owns n=16t+j -> contiguous at 17t+j (17 odd ->
//              banks bijective over lanes, 2-way)
//       read:  n' = (t_hi<<8)|(j<<4)|t_lo -> 272*t_hi + 17*j + t_lo
//              (272 = 16 mod 32 -> 2-way)
//   T2: element n at buf[17*(n&255) + (n>>8)]
//       write: 272*j + 17*t_lo + t_hi (17r+u pattern -> exactly 2-way)
//       read:  contiguous at 17t + j

constexpr int DIM = 4096;

__device__ __forceinline__ void fwht16(float v[16]) {
#pragma unroll
    for (int h = 1; h < 16; h <<= 1) {
#pragma unroll
        for (int i = 0; i < 16; i += 2 * h) {
#pragma unroll
            for (int k = 0; k < h; ++k) {
                float a = v[i + k];
                float b = v[i + k + h];
                v[i + k]     = a + b;
                v[i + k + h] = a - b;
            }
        }
    }
}

__global__ __launch_bounds__(256, 8) void fwht4096_kernel(const float* __restrict__ x,
                                                          float* __restrict__ y) {
    __shared__ float buf[17 * 256];  // 17,408 B
    const int t = threadIdx.x;             // 0..255
    const long long row = blockIdx.x;      // one row per block
    const int t_hi = t >> 4;               // bits 8..11 owner (after T1)
    const int t_lo = t & 15;               // bits 0..3 owner (after T1)

    float v[16];

    // ---- load: thread owns n = 16t + j, j = 0..15 (4 x float4) ----
    {
        const float4* src = reinterpret_cast<const float4*>(x + row * DIM + t * 16);
#pragma unroll
        for (int q = 0; q < 4; ++q) {
            float4 f = src[q];
            v[4 * q + 0] = f.x;
            v[4 * q + 1] = f.y;
            v[4 * q + 2] = f.z;
            v[4 * q + 3] = f.w;
        }
    }

    // ---- phase A: butterflies on bits 0..3 (register index j) ----
    fwht16(v);

    // ---- transpose 1: A1(n) = 17*(n>>4) + (n&15) ----
    {
        float* wp = buf + 17 * t;  // n>>4 = t, n&15 = j
#pragma unroll
        for (int j = 0; j < 16; ++j) wp[j] = v[j];
    }
    __syncthreads();
    // read n' = (t_hi<<8) | (j<<4) | t_lo  ->  addr 272*t_hi + 17*j + t_lo
    {
        const float* rp = buf + 272 * t_hi + t_lo;
#pragma unroll
        for (int j = 0; j < 16; ++j) v[j] = rp[17 * j];
    }

    // ---- phase B: butterflies on bits 4..7 (register index j) ----
    fwht16(v);

    __syncthreads();  // all T1 reads done before relayout

    // ---- transpose 2: A2(n) = 17*(n&255) + (n>>8) ----
    // value j has n' = (t_hi<<8)|(j<<4)|t_lo -> addr 272*j + 17*t_lo + t_hi
    {
        float* wp = buf + 17 * t_lo + t_hi;
#pragma unroll
        for (int j = 0; j < 16; ++j) wp[272 * j] = v[j];
    }
    __syncthreads();
    // read n'' = (j<<8) | t  ->  addr 17*t + j (contiguous)
    {
        const float* rp = buf + 17 * t;
#pragma unroll
        for (int j = 0; j < 16; ++j) v[j] = rp[j];
    }

    // ---- phase C: butterflies on bits 8..11 (register index j) ----
    fwht16(v);

    // ---- scale + store: value j sits at n = j*256 + t (coalesced per j) ----
    const float scale = 0x1p-39f;  // 2^-(L(L+1)/4), L = 12
    float* dst = y + row * DIM + t;
#pragma unroll
    for (int j = 0; j < 16; ++j) {
        dst[j * 256] = v[j] * scale;
    }
}

extern "C" void kernel_launch(void* const* d_in, const int* in_sizes, int n_in,
                              void* d_out, int out_size, void* d_ws, size_t ws_size,
                              hipStream_t stream) {
    const float* x = (const float*)d_in[0];
    float* y = (float*)d_out;
    const int nrows = in_sizes[0] / DIM;  // 8192
    fwht4096_kernel<<<nrows, 256, 0, stream>>>(x, y);
}